// Round 7
// baseline (196.469 us; speedup 1.0000x reference)
//
#include <hip/hip_runtime.h>
#include <stdint.h>

#define B_ 8
#define T_ 1024
#define C_ 768
#define H_ 12
#define DK 64
#define BT (B_*T_)      // 8192
#define NQKV (3*C_)     // 2304

typedef unsigned short u16;
typedef __bf16 bf16x8 __attribute__((ext_vector_type(8)));
typedef __bf16 bf16x4 __attribute__((ext_vector_type(4)));
typedef float  f32x4  __attribute__((ext_vector_type(4)));

typedef const __attribute__((address_space(1))) void gvoid_t;
typedef __attribute__((address_space(3))) void lvoid_t;

// Raw s_barrier is NOT a compiler fence (LLVM IntrNoMem) — R6's replay race.
// asm volatile + "memory" clobber = compiler-only fence, zero extra instrs,
// preserves fine-grained vmcnt pipeline (no vmcnt(0) drain like __syncthreads).
#define SBARRIER()  asm volatile("s_barrier" ::: "memory")
#define SWAITCNT(s) asm volatile("s_waitcnt " s ::: "memory")

__device__ __forceinline__ void gl_lds16(const void* g, void* l) {
    __builtin_amdgcn_global_load_lds((gvoid_t*)g, (lvoid_t*)l, 16, 0, 0);
}

__device__ __forceinline__ u16 f2b(float f) {
    union { float f; unsigned int u; } v; v.f = f;
    unsigned int u = v.u;
    return (u16)((u + 0x7fffu + ((u >> 16) & 1u)) >> 16);
}

__device__ __forceinline__ f32x4 mfma16(bf16x8 a, bf16x8 b, f32x4 c) {
    return __builtin_amdgcn_mfma_f32_16x16x32_bf16(a, b, c, 0, 0, 0);
}

// ---------- convert f32 -> bf16 (vectorized x4) ----------
__global__ void k_convert(const float* __restrict__ in, u16* __restrict__ out, int n4) {
    int i = blockIdx.x * blockDim.x + threadIdx.x;
    if (i < n4) {
        float4 f = ((const float4*)in)[i];
        uint2 o;
        o.x = (unsigned)f2b(f.x) | ((unsigned)f2b(f.y) << 16);
        o.y = (unsigned)f2b(f.z) | ((unsigned)f2b(f.w) << 16);
        ((uint2*)out)[i] = o;
    }
}

// ---------- tiled convert + transpose: W[K,N] f32 -> Wt[N,K] bf16 ----------
__global__ __launch_bounds__(256)
void k_transpose_convert(const float* __restrict__ w, u16* __restrict__ wt,
                         int K, int N) {
    __shared__ u16 tile[32][34];
    const int tx = threadIdx.x, ty = threadIdx.y;   // 32 x 8
    const int n0 = blockIdx.x * 32, k0 = blockIdx.y * 32;
    #pragma unroll
    for (int i = 0; i < 4; i++)
        tile[ty + i * 8][tx] = f2b(w[(size_t)(k0 + ty + i * 8) * N + n0 + tx]);
    __syncthreads();
    #pragma unroll
    for (int i = 0; i < 4; i++)
        wt[(size_t)(n0 + ty + i * 8) * K + k0 + tx] = tile[tx][ty + i * 8];
}

// ---------- QKV GEMM: 256x128 tile, 3-stage dist-2 pipeline ----------
__global__ __launch_bounds__(256, 2)
void k_gemm_qkv(const u16* __restrict__ A, const u16* __restrict__ Bt,
                const float* __restrict__ bias,
                u16* __restrict__ qo, u16* __restrict__ ko, u16* __restrict__ vto)
{
    const int K = C_;
    __shared__ u16 As[3][256 * 32];   // 3 x 16 KB
    __shared__ u16 Bs[3][128 * 32];   // 3 x  8 KB  (72 KB -> 2 blocks/CU)
    const int tid  = threadIdx.x;
    const int lane = tid & 63;
    const int w    = tid >> 6;
    const int quad = lane >> 4;
    const int col  = lane & 15;

    const int id   = blockIdx.x;          // 0..575
    const int xcd  = id & 7;
    const int slot = id >> 3;             // 0..71
    const int m0   = (xcd * 4 + (slot & 3)) * 256;
    const int n0   = (slot >> 2) * 128;

    f32x4 zero4 = {0.f, 0.f, 0.f, 0.f};
    f32x4 acc[4][8];
    #pragma unroll
    for (int i = 0; i < 4; i++)
        #pragma unroll
        for (int j = 0; j < 8; j++) acc[i][j] = zero4;

    const int srl = lane >> 2;
    const int scc = ((lane & 3) ^ ((lane >> 3) & 3)) * 8;
    const u16* gA = A  + (size_t)(m0 + w * 16 + srl) * K + scc;
    const u16* gB = Bt + (size_t)(n0 + w * 16 + srl) * K + scc;

    const int NIT = K >> 5;   // 24

    #define STAGE(kt, bufi)                                                            \
        do {                                                                           \
            gl_lds16(gA + (kt),                   (char*)As[bufi] + w * 1024);         \
            gl_lds16(gA + (size_t)64  * K + (kt), (char*)As[bufi] + 4096  + w * 1024); \
            gl_lds16(gA + (size_t)128 * K + (kt), (char*)As[bufi] + 8192  + w * 1024); \
            gl_lds16(gA + (size_t)192 * K + (kt), (char*)As[bufi] + 12288 + w * 1024); \
            gl_lds16(gB + (kt),                   (char*)Bs[bufi] + w * 1024);         \
            gl_lds16(gB + (size_t)64  * K + (kt), (char*)Bs[bufi] + 4096  + w * 1024); \
        } while (0)

    STAGE(0, 0);
    STAGE(32, 1);
    int cur = 0;
    const int sw = ((col >> 1) & 3);      // fragment-read swizzle (2-way, free)
    for (int it = 0; it < NIT; ++it) {
        SBARRIER();                        // readers of buf[(cur+2)%3] done
        if (it + 2 < NIT) {
            int b2 = cur + 2; if (b2 >= 3) b2 -= 3;
            STAGE((it + 2) << 5, b2);      // dist-2 prefetch, 6 loads/wave
            SWAITCNT("vmcnt(12)");         // drain tile `it`
        } else if (it + 1 < NIT) {
            SWAITCNT("vmcnt(6)");
        } else {
            SWAITCNT("vmcnt(0)");
        }
        SBARRIER();                        // all waves' buf[cur] landed

        const u16* Ab = As[cur];
        const u16* Bb = Bs[cur];
        bf16x8 af[4], bfr[8];
        #pragma unroll
        for (int mt = 0; mt < 4; mt++) {
            int row = w * 64 + mt * 16 + col;
            af[mt] = *(const bf16x8*)&Ab[row * 32 + ((quad ^ sw) * 8)];
        }
        #pragma unroll
        for (int nt = 0; nt < 8; nt++) {
            int row = nt * 16 + col;
            bfr[nt] = *(const bf16x8*)&Bb[row * 32 + ((quad ^ sw) * 8)];
        }
        #pragma unroll
        for (int mt = 0; mt < 4; mt++)
            #pragma unroll
            for (int nt = 0; nt < 8; nt++)
                acc[mt][nt] = mfma16(af[mt], bfr[nt], acc[mt][nt]);

        cur = (cur == 2) ? 0 : cur + 1;
    }
    #undef STAGE

    #pragma unroll
    for (int mt = 0; mt < 4; mt++) {
        #pragma unroll
        for (int nt = 0; nt < 8; nt++) {
            #pragma unroll
            for (int r = 0; r < 4; r++) {
                int m = m0 + w * 64 + mt * 16 + quad * 4 + r;
                int n = n0 + nt * 16 + col;
                float v = acc[mt][nt][r] + bias[n];
                int sec = n / C_;
                int c   = n - sec * C_;
                int h   = c >> 6;
                int d   = c & 63;
                int b   = m >> 10;
                int t   = m & 1023;
                int bh  = b * H_ + h;
                u16 bv  = f2b(v);
                if (sec == 0)      qo [((size_t)bh * T_ + t) * DK + d] = bv;
                else if (sec == 1) ko [((size_t)bh * T_ + t) * DK + d] = bv;
                else               vto[((size_t)bh * DK + d) * T_ + t] = bv;
            }
        }
    }
}

// ---------- out-proj GEMM: 128x128 tile, 3-stage dist-2 ----------
__global__ __launch_bounds__(256, 3)
void k_gemm_out(const u16* __restrict__ A, const u16* __restrict__ Bt,
                const float* __restrict__ bias, float* __restrict__ outf,
                int M, int N, int K)
{
    __shared__ u16 As[3][128 * 32];
    __shared__ u16 Bs[3][128 * 32];
    const int tid  = threadIdx.x;
    const int lane = tid & 63;
    const int w    = tid >> 6;
    const int quad = lane >> 4;
    const int col  = lane & 15;

    const int id   = blockIdx.x + gridDim.x * blockIdx.y;
    const int xcd  = id & 7;
    const int slot = id >> 3;
    const int m0   = (xcd * 8 + (slot & 7)) * 128;
    const int n0   = (slot >> 3) * 128;

    const int wm   = (w >> 1) * 64;
    const int wn   = (w & 1) * 64;

    f32x4 zero4 = {0.f, 0.f, 0.f, 0.f};
    f32x4 acc[4][4];
    #pragma unroll
    for (int i = 0; i < 4; i++)
        #pragma unroll
        for (int j = 0; j < 4; j++) acc[i][j] = zero4;

    const int sr  = tid >> 2;
    const int scc = ((tid & 3) ^ ((sr >> 1) & 3)) * 8;
    const u16* gA = A  + (size_t)(m0 + sr) * K + scc;
    const u16* gB = Bt + (size_t)(n0 + sr) * K + scc;

    const int NIT = K >> 5;

    #define STAGE(kt, bufi)                                                          \
        do {                                                                         \
            gl_lds16(gA + (kt),                  (char*)As[bufi] + w * 1024);        \
            gl_lds16(gA + (size_t)64 * K + (kt), (char*)As[bufi] + 4096 + w * 1024); \
            gl_lds16(gB + (kt),                  (char*)Bs[bufi] + w * 1024);        \
            gl_lds16(gB + (size_t)64 * K + (kt), (char*)Bs[bufi] + 4096 + w * 1024); \
        } while (0)

    STAGE(0, 0);
    STAGE(32, 1);
    int cur = 0;
    for (int it = 0; it < NIT; ++it) {
        SBARRIER();
        if (it + 2 < NIT) {
            int b2 = cur + 2; if (b2 >= 3) b2 -= 3;
            STAGE((it + 2) << 5, b2);
            SWAITCNT("vmcnt(8)");
        } else if (it + 1 < NIT) {
            SWAITCNT("vmcnt(4)");
        } else {
            SWAITCNT("vmcnt(0)");
        }
        SBARRIER();

        const u16* Ab = As[cur];
        const u16* Bb = Bs[cur];
        bf16x8 af[4], bfr[4];
        #pragma unroll
        for (int mt = 0; mt < 4; mt++) {
            int row = wm + mt * 16 + col;
            af[mt] = *(const bf16x8*)&Ab[row * 32 + ((quad ^ ((row >> 1) & 3)) * 8)];
        }
        #pragma unroll
        for (int nt = 0; nt < 4; nt++) {
            int row = wn + nt * 16 + col;
            bfr[nt] = *(const bf16x8*)&Bb[row * 32 + ((quad ^ ((row >> 1) & 3)) * 8)];
        }
        #pragma unroll
        for (int mt = 0; mt < 4; mt++)
            #pragma unroll
            for (int nt = 0; nt < 4; nt++)
                acc[mt][nt] = mfma16(af[mt], bfr[nt], acc[mt][nt]);

        cur = (cur == 2) ? 0 : cur + 1;
    }
    #undef STAGE

    #pragma unroll
    for (int mt = 0; mt < 4; mt++) {
        #pragma unroll
        for (int nt = 0; nt < 4; nt++) {
            #pragma unroll
            for (int r = 0; r < 4; r++) {
                int m = m0 + wm + mt * 16 + quad * 4 + r;
                int n = n0 + wn + nt * 16 + col;
                outf[(size_t)m * N + n] = acc[mt][nt][r] + bias[n];
            }
        }
    }
}

// ---------- causal flash attention, dbuf K/V staging ----------
#define PSTRIDE 72   // u16 elems; 144B rows

__device__ __forceinline__ bf16x8 ld_sw(const u16* base, int row, int half,
                                        int quad, int c7) {
    return *(const bf16x8*)(base + row * DK + (((half * 4 + quad) ^ c7) * 8));
}

template <bool MASK>
__device__ __forceinline__ void attn_chunk(
    const u16* Ks, const u16* Vs, __bf16* pbuf,
    const bf16x8 (&qf)[2][2], bf16x8 ones,
    int kv0, int qw, int quad, int col,
    f32x4 (&oacc)[2][4], f32x4 (&lacc)[2])
{
    const int c7 = col & 7;
    f32x4 zero4 = {0.f, 0.f, 0.f, 0.f};
    f32x4 st[2][4];
    #pragma unroll
    for (int g = 0; g < 4; g++) {
        bf16x8 klo = ld_sw(Ks, g * 16 + col, 0, quad, c7);
        bf16x8 khi = ld_sw(Ks, g * 16 + col, 1, quad, c7);
        st[0][g] = mfma16(khi, qf[0][1], mfma16(klo, qf[0][0], zero4));
        st[1][g] = mfma16(khi, qf[1][1], mfma16(klo, qf[1][0], zero4));
    }
    const float scl = 0.18033688f;   // log2(e)/8
    #pragma unroll
    for (int s = 0; s < 2; s++) {
        __bf16* pb = pbuf + s * 16 * PSTRIDE + col * PSTRIDE;
        #pragma unroll
        for (int g = 0; g < 4; g++) {
            bf16x4 pp;
            #pragma unroll
            for (int r = 0; r < 4; r++) {
                float p = __builtin_amdgcn_exp2f(st[s][g][r] * scl - 12.0f);
                if (MASK) {
                    int kv = kv0 + g * 16 + quad * 4 + r;
                    if (kv > qw + s * 16 + col) p = 0.f;
                }
                pp[r] = (__bf16)p;
            }
            *(bf16x4*)(pb + g * 16 + quad * 4) = pp;
        }
    }
    SWAITCNT("lgkmcnt(0)");   // wave-local LDS ordering for P round-trip
    bf16x8 pf[2][2];
    #pragma unroll
    for (int s = 0; s < 2; s++) {
        const __bf16* pb = pbuf + s * 16 * PSTRIDE + col * PSTRIDE;
        pf[s][0] = *(const bf16x8*)(pb + quad * 8);
        pf[s][1] = *(const bf16x8*)(pb + 32 + quad * 8);
        lacc[s] = mfma16(pf[s][1], ones, mfma16(pf[s][0], ones, lacc[s]));
    }
    #pragma unroll
    for (int dt = 0; dt < 4; dt++) {
        bf16x8 vlo = ld_sw(Vs, dt * 16 + col, 0, quad, c7);
        bf16x8 vhi = ld_sw(Vs, dt * 16 + col, 1, quad, c7);
        #pragma unroll
        for (int s = 0; s < 2; s++)
            oacc[s][dt] = mfma16(pf[s][1], vhi, mfma16(pf[s][0], vlo, oacc[s][dt]));
    }
}

__global__ __launch_bounds__(256, 3)
void k_attn(const u16* __restrict__ Q, const u16* __restrict__ Kf,
            const u16* __restrict__ Vt, u16* __restrict__ Of)
{
    __shared__ u16 Ks[2][64 * DK];
    __shared__ u16 Vs[2][64 * DK];
    __shared__ __bf16 Plds[4][32 * PSTRIDE];
    const int bh   = blockIdx.x;
    const int b    = bh / H_;
    const int h    = bh - b * H_;
    const int tid  = threadIdx.x;
    const int lane = tid & 63;
    const int w    = tid >> 6;
    const int quad = lane >> 4;
    const int col  = lane & 15;
    const int ty   = 7 - (int)blockIdx.y;
    const int nch  = 2 * ty + 2;
    const int qw   = ty * 128 + w * 32;
    __bf16* pbuf = Plds[w];

    const u16* Qb = Q  + (size_t)bh * T_ * DK;
    const u16* Kb = Kf + (size_t)bh * T_ * DK;
    const u16* Vb = Vt + (size_t)bh * DK * T_;

    int sG0 = tid, sG1 = 256 + tid;
    int sr0 = sG0 >> 3, sg0 = (sG0 & 7) ^ (sr0 & 7);
    int sr1 = sG1 >> 3, sg1 = (sG1 & 7) ^ (sr1 & 7);

    bf16x8 qf[2][2];
    #pragma unroll
    for (int s = 0; s < 2; s++) {
        const u16* qp = Qb + (size_t)(qw + s * 16 + col) * DK;
        qf[s][0] = *(const bf16x8*)(qp + quad * 8);
        qf[s][1] = *(const bf16x8*)(qp + 32 + quad * 8);
    }

    bf16x8 ones;
    #pragma unroll
    for (int i = 0; i < 8; i++) ((u16*)&ones)[i] = 0x3F80;

    f32x4 zero4 = {0.f, 0.f, 0.f, 0.f};
    f32x4 oacc[2][4];
    f32x4 lacc[2] = {zero4, zero4};
    #pragma unroll
    for (int s = 0; s < 2; s++)
        #pragma unroll
        for (int dt = 0; dt < 4; dt++) oacc[s][dt] = zero4;

    #define ASTAGE(c, bufi)                                                            \
        do {                                                                           \
            int kvs = (c) * 64;                                                        \
            gl_lds16(Kb + (size_t)(kvs + sr0) * DK + sg0 * 8, (char*)Ks[bufi] + w * 1024);        \
            gl_lds16(Kb + (size_t)(kvs + sr1) * DK + sg1 * 8, (char*)Ks[bufi] + 4096 + w * 1024); \
            gl_lds16(Vb + (size_t)sr0 * T_ + kvs + sg0 * 8,   (char*)Vs[bufi] + w * 1024);        \
            gl_lds16(Vb + (size_t)sr1 * T_ + kvs + sg1 * 8,   (char*)Vs[bufi] + 4096 + w * 1024); \
        } while (0)

    ASTAGE(0, 0);
    #pragma unroll 1
    for (int c = 0; c < nch; ++c) {
        const int cur = c & 1;
        SBARRIER();                        // readers of buf[!cur] done
        if (c + 1 < nch) {
            ASTAGE(c + 1, cur ^ 1);
            SWAITCNT("vmcnt(4)");
        } else {
            SWAITCNT("vmcnt(0)");
        }
        SBARRIER();                        // all waves' buf[cur] staged

        const int kv0 = c * 64;
        if (kv0 <= qw + 31) {
            if (kv0 + 63 <= qw)
                attn_chunk<false>(Ks[cur], Vs[cur], pbuf, qf, ones, kv0, qw, quad, col, oacc, lacc);
            else
                attn_chunk<true>(Ks[cur], Vs[cur], pbuf, qf, ones, kv0, qw, quad, col, oacc, lacc);
        }
    }
    #undef ASTAGE

    #pragma unroll
    for (int s = 0; s < 2; s++) {
        #pragma unroll
        for (int r = 0; r < 4; r++) {
            float inv = 1.f / lacc[s][r];
            int t = qw + s * 16 + quad * 4 + r;
            u16* op = Of + ((size_t)(b * T_ + t)) * C_ + h * DK;
            #pragma unroll
            for (int dt = 0; dt < 4; dt++) op[dt * 16 + col] = f2b(oacc[s][dt][r] * inv);
        }
    }
}

extern "C" void kernel_launch(void* const* d_in, const int* in_sizes, int n_in,
                              void* d_out, int out_size, void* d_ws, size_t ws_size,
                              hipStream_t stream) {
    const float* x    = (const float*)d_in[0];
    const float* Wqkv = (const float*)d_in[1];
    const float* bqkv = (const float*)d_in[2];
    const float* Wout = (const float*)d_in[3];
    const float* bout = (const float*)d_in[4];
    float* out = (float*)d_out;

    char* ws = (char*)d_ws;
    u16* xb    = (u16*)(ws);                    // 8192*768     bf16 = 12.0 MiB
    u16* wqkvT = (u16*)(ws + 12582912);         // [2304,768]   bf16
    u16* woutT = (u16*)(ws + 16121856);         // [768,768]    bf16
    u16* qw    = (u16*)(ws + 17301504);         // [96,1024,64] bf16
    u16* kw    = (u16*)(ws + 29884416);         // [96,1024,64] bf16
    u16* vtw   = (u16*)(ws + 42467328);         // [96,64,1024] bf16
    u16* aw    = (u16*)(ws + 55050240);         // [8192,768]   bf16  (end ~67.6 MB)

    k_convert<<<(BT * C_ / 4) / 256, 256, 0, stream>>>(x, xb, BT * C_ / 4);
    k_transpose_convert<<<dim3(NQKV / 32, C_ / 32), dim3(32, 8), 0, stream>>>(Wqkv, wqkvT, C_, NQKV);
    k_transpose_convert<<<dim3(C_ / 32, C_ / 32), dim3(32, 8), 0, stream>>>(Wout, woutT, C_, C_);

    // 256x128 tiles: 32 m-tiles x 18 n-tiles = 576 blocks
    k_gemm_qkv<<<576, 256, 0, stream>>>(xb, wqkvT, bqkv, qw, kw, vtw);

    k_attn<<<dim3(B_ * H_, 8), 256, 0, stream>>>(qw, kw, vtw, aw);

    k_gemm_out<<<dim3(C_ / 128, BT / 128), 256, 0, stream>>>(
        aw, woutT, bout, out, BT, C_, C_);
}

// Round 8
// 189.124 us; speedup vs baseline: 1.0388x; 1.0388x over previous
//
#include <hip/hip_runtime.h>
#include <stdint.h>

#define B_ 8
#define T_ 1024
#define C_ 768
#define H_ 12
#define DK 64
#define BT (B_*T_)      // 8192
#define NQKV (3*C_)     // 2304

typedef unsigned short u16;
typedef __bf16 bf16x8 __attribute__((ext_vector_type(8)));
typedef __bf16 bf16x4 __attribute__((ext_vector_type(4)));
typedef float  f32x4  __attribute__((ext_vector_type(4)));

typedef const __attribute__((address_space(1))) void gvoid_t;
typedef __attribute__((address_space(3))) void lvoid_t;

// Raw s_barrier is NOT a compiler fence (LLVM IntrNoMem) — caused R6's replay
// race. asm volatile + "memory" clobber = compiler-only fence, zero extra
// instructions, preserves fine-grained vmcnt pipelining.
#define SBARRIER()  asm volatile("s_barrier" ::: "memory")
#define SWAITCNT(s) asm volatile("s_waitcnt " s ::: "memory")

__device__ __forceinline__ void gl_lds16(const void* g, void* l) {
    __builtin_amdgcn_global_load_lds((gvoid_t*)g, (lvoid_t*)l, 16, 0, 0);
}

__device__ __forceinline__ u16 f2b(float f) {
    union { float f; unsigned int u; } v; v.f = f;
    unsigned int u = v.u;
    return (u16)((u + 0x7fffu + ((u >> 16) & 1u)) >> 16);
}

__device__ __forceinline__ f32x4 mfma16(bf16x8 a, bf16x8 b, f32x4 c) {
    return __builtin_amdgcn_mfma_f32_16x16x32_bf16(a, b, c, 0, 0, 0);
}

// ---------- convert f32 -> bf16 (vectorized x4) ----------
__global__ void k_convert(const float* __restrict__ in, u16* __restrict__ out, int n4) {
    int i = blockIdx.x * blockDim.x + threadIdx.x;
    if (i < n4) {
        float4 f = ((const float4*)in)[i];
        uint2 o;
        o.x = (unsigned)f2b(f.x) | ((unsigned)f2b(f.y) << 16);
        o.y = (unsigned)f2b(f.z) | ((unsigned)f2b(f.w) << 16);
        ((uint2*)out)[i] = o;
    }
}

// ---------- tiled convert + transpose: W[K,N] f32 -> Wt[N,K] bf16 ----------
__global__ __launch_bounds__(256)
void k_transpose_convert(const float* __restrict__ w, u16* __restrict__ wt,
                         int K, int N) {
    __shared__ u16 tile[32][34];
    const int tx = threadIdx.x, ty = threadIdx.y;   // 32 x 8
    const int n0 = blockIdx.x * 32, k0 = blockIdx.y * 32;
    #pragma unroll
    for (int i = 0; i < 4; i++)
        tile[ty + i * 8][tx] = f2b(w[(size_t)(k0 + ty + i * 8) * N + n0 + tx]);
    __syncthreads();
    #pragma unroll
    for (int i = 0; i < 4; i++)
        wt[(size_t)(n0 + ty + i * 8) * K + k0 + tx] = tile[tx][ty + i * 8];
}

// ---------- QKV GEMM: 128x128 tile, 3-stage dist-2 (R5 proven structure) ----------
// R7 lesson: 256x128 tile cut residency 3->2 blocks/CU and added a 1.5-round
// tail -> 63->102us. TLP beats barrier amortization at this scale.
__global__ __launch_bounds__(256, 3)
void k_gemm_qkv(const u16* __restrict__ A, const u16* __restrict__ Bt,
                const float* __restrict__ bias,
                u16* __restrict__ qo, u16* __restrict__ ko, u16* __restrict__ vto)
{
    const int K = C_;
    __shared__ u16 As[3][128 * 32];
    __shared__ u16 Bs[3][128 * 32];   // 48 KB -> 3 blocks/CU
    const int tid  = threadIdx.x;
    const int lane = tid & 63;
    const int w    = tid >> 6;
    const int quad = lane >> 4;
    const int col  = lane & 15;

    const int id   = blockIdx.x + gridDim.x * blockIdx.y;  // grid (18, 64)
    const int xcd  = id & 7;
    const int slot = id >> 3;
    const int m0   = (xcd * 8 + (slot & 7)) * 128;
    const int n0   = (slot >> 3) * 128;

    const int wm   = (w >> 1) * 64;
    const int wn   = (w & 1) * 64;

    f32x4 zero4 = {0.f, 0.f, 0.f, 0.f};
    f32x4 acc[4][4];
    #pragma unroll
    for (int i = 0; i < 4; i++)
        #pragma unroll
        for (int j = 0; j < 4; j++) acc[i][j] = zero4;

    const int sr  = tid >> 2;
    const int scc = ((tid & 3) ^ ((sr >> 1) & 3)) * 8;
    const u16* gA = A  + (size_t)(m0 + sr) * K + scc;
    const u16* gB = Bt + (size_t)(n0 + sr) * K + scc;

    const int NIT = K >> 5;   // 24

    #define STAGE(kt, bufi)                                                          \
        do {                                                                         \
            gl_lds16(gA + (kt),                  (char*)As[bufi] + w * 1024);        \
            gl_lds16(gA + (size_t)64 * K + (kt), (char*)As[bufi] + 4096 + w * 1024); \
            gl_lds16(gB + (kt),                  (char*)Bs[bufi] + w * 1024);        \
            gl_lds16(gB + (size_t)64 * K + (kt), (char*)Bs[bufi] + 4096 + w * 1024); \
        } while (0)

    STAGE(0, 0);
    STAGE(32, 1);
    int cur = 0;
    for (int it = 0; it < NIT; ++it) {
        SBARRIER();                        // readers of buf[(cur+2)%3] done
        if (it + 2 < NIT) {
            int b2 = cur + 2; if (b2 >= 3) b2 -= 3;
            STAGE((it + 2) << 5, b2);
            SWAITCNT("vmcnt(8)");          // drain tile `it` (issued 2 iters ago)
        } else if (it + 1 < NIT) {
            SWAITCNT("vmcnt(4)");
        } else {
            SWAITCNT("vmcnt(0)");
        }
        SBARRIER();                        // all waves' buf[cur] landed

        const u16* Ab = As[cur];
        const u16* Bb = Bs[cur];
        bf16x8 af[4], bfr[4];
        #pragma unroll
        for (int mt = 0; mt < 4; mt++) {
            int row = wm + mt * 16 + col;
            af[mt] = *(const bf16x8*)&Ab[row * 32 + ((quad ^ ((row >> 1) & 3)) * 8)];
        }
        #pragma unroll
        for (int nt = 0; nt < 4; nt++) {
            int row = wn + nt * 16 + col;
            bfr[nt] = *(const bf16x8*)&Bb[row * 32 + ((quad ^ ((row >> 1) & 3)) * 8)];
        }
        #pragma unroll
        for (int mt = 0; mt < 4; mt++)
            #pragma unroll
            for (int nt = 0; nt < 4; nt++)
                acc[mt][nt] = mfma16(af[mt], bfr[nt], acc[mt][nt]);

        cur = (cur == 2) ? 0 : cur + 1;
    }
    #undef STAGE

    #pragma unroll
    for (int mt = 0; mt < 4; mt++) {
        #pragma unroll
        for (int nt = 0; nt < 4; nt++) {
            #pragma unroll
            for (int r = 0; r < 4; r++) {
                int m = m0 + wm + mt * 16 + quad * 4 + r;
                int n = n0 + wn + nt * 16 + col;
                float v = acc[mt][nt][r] + bias[n];
                int sec = n / C_;
                int c   = n - sec * C_;
                int h   = c >> 6;
                int d   = c & 63;
                int b   = m >> 10;
                int t   = m & 1023;
                int bh  = b * H_ + h;
                u16 bv  = f2b(v);
                if (sec == 0)      qo [((size_t)bh * T_ + t) * DK + d] = bv;
                else if (sec == 1) ko [((size_t)bh * T_ + t) * DK + d] = bv;
                else               vto[((size_t)bh * DK + d) * T_ + t] = bv;
            }
        }
    }
}

// ---------- out-proj GEMM: 128x128, 4-stage dist-3 pipeline ----------
// Only 384 blocks (~1.5/CU) -> residency is dispatch-limited, so 64 KB LDS is
// free; deeper prefetch (3 iters of slack) for the latency-bound small grid.
__global__ __launch_bounds__(256, 2)
void k_gemm_out(const u16* __restrict__ A, const u16* __restrict__ Bt,
                const float* __restrict__ bias, float* __restrict__ outf,
                int M, int N, int K)
{
    __shared__ u16 As[4][128 * 32];
    __shared__ u16 Bs[4][128 * 32];   // 64 KB
    const int tid  = threadIdx.x;
    const int lane = tid & 63;
    const int w    = tid >> 6;
    const int quad = lane >> 4;
    const int col  = lane & 15;

    const int id   = blockIdx.x + gridDim.x * blockIdx.y;   // grid (6, 64)
    const int xcd  = id & 7;
    const int slot = id >> 3;
    const int m0   = (xcd * 8 + (slot & 7)) * 128;
    const int n0   = (slot >> 3) * 128;

    const int wm   = (w >> 1) * 64;
    const int wn   = (w & 1) * 64;

    f32x4 zero4 = {0.f, 0.f, 0.f, 0.f};
    f32x4 acc[4][4];
    #pragma unroll
    for (int i = 0; i < 4; i++)
        #pragma unroll
        for (int j = 0; j < 4; j++) acc[i][j] = zero4;

    const int sr  = tid >> 2;
    const int scc = ((tid & 3) ^ ((sr >> 1) & 3)) * 8;
    const u16* gA = A  + (size_t)(m0 + sr) * K + scc;
    const u16* gB = Bt + (size_t)(n0 + sr) * K + scc;

    const int NIT = K >> 5;   // 24

    #define STAGE(kt, bufi)                                                          \
        do {                                                                         \
            gl_lds16(gA + (kt),                  (char*)As[bufi] + w * 1024);        \
            gl_lds16(gA + (size_t)64 * K + (kt), (char*)As[bufi] + 4096 + w * 1024); \
            gl_lds16(gB + (kt),                  (char*)Bs[bufi] + w * 1024);        \
            gl_lds16(gB + (size_t)64 * K + (kt), (char*)Bs[bufi] + 4096 + w * 1024); \
        } while (0)

    STAGE(0, 0);
    STAGE(32, 1);
    STAGE(64, 2);
    int cur = 0;
    for (int it = 0; it < NIT; ++it) {
        SBARRIER();                        // readers of buf[(cur+3)&3] done
        if (it + 3 < NIT) {
            STAGE((it + 3) << 5, (cur + 3) & 3);
            SWAITCNT("vmcnt(12)");         // tiles it..it+3 outstanding: drain `it`
        } else if (it + 2 < NIT) {
            SWAITCNT("vmcnt(8)");
        } else if (it + 1 < NIT) {
            SWAITCNT("vmcnt(4)");
        } else {
            SWAITCNT("vmcnt(0)");
        }
        SBARRIER();                        // all waves' buf[cur] landed

        const u16* Ab = As[cur];
        const u16* Bb = Bs[cur];
        bf16x8 af[4], bfr[4];
        #pragma unroll
        for (int mt = 0; mt < 4; mt++) {
            int row = wm + mt * 16 + col;
            af[mt] = *(const bf16x8*)&Ab[row * 32 + ((quad ^ ((row >> 1) & 3)) * 8)];
        }
        #pragma unroll
        for (int nt = 0; nt < 4; nt++) {
            int row = wn + nt * 16 + col;
            bfr[nt] = *(const bf16x8*)&Bb[row * 32 + ((quad ^ ((row >> 1) & 3)) * 8)];
        }
        #pragma unroll
        for (int mt = 0; mt < 4; mt++)
            #pragma unroll
            for (int nt = 0; nt < 4; nt++)
                acc[mt][nt] = mfma16(af[mt], bfr[nt], acc[mt][nt]);

        cur = (cur + 1) & 3;
    }
    #undef STAGE

    #pragma unroll
    for (int mt = 0; mt < 4; mt++) {
        #pragma unroll
        for (int nt = 0; nt < 4; nt++) {
            #pragma unroll
            for (int r = 0; r < 4; r++) {
                int m = m0 + wm + mt * 16 + quad * 4 + r;
                int n = n0 + wn + nt * 16 + col;
                outf[(size_t)m * N + n] = acc[mt][nt][r] + bias[n];
            }
        }
    }
}

// ---------- causal flash attention, dbuf K/V staging ----------
#define PSTRIDE 72   // u16 elems; 144B rows

__device__ __forceinline__ bf16x8 ld_sw(const u16* base, int row, int half,
                                        int quad, int c7) {
    return *(const bf16x8*)(base + row * DK + (((half * 4 + quad) ^ c7) * 8));
}

template <bool MASK>
__device__ __forceinline__ void attn_chunk(
    const u16* Ks, const u16* Vs, __bf16* pbuf,
    const bf16x8 (&qf)[2][2], bf16x8 ones,
    int kv0, int qw, int quad, int col,
    f32x4 (&oacc)[2][4], f32x4 (&lacc)[2])
{
    const int c7 = col & 7;
    f32x4 zero4 = {0.f, 0.f, 0.f, 0.f};
    f32x4 st[2][4];
    #pragma unroll
    for (int g = 0; g < 4; g++) {
        bf16x8 klo = ld_sw(Ks, g * 16 + col, 0, quad, c7);
        bf16x8 khi = ld_sw(Ks, g * 16 + col, 1, quad, c7);
        st[0][g] = mfma16(khi, qf[0][1], mfma16(klo, qf[0][0], zero4));
        st[1][g] = mfma16(khi, qf[1][1], mfma16(klo, qf[1][0], zero4));
    }
    const float scl = 0.18033688f;   // log2(e)/8
    #pragma unroll
    for (int s = 0; s < 2; s++) {
        __bf16* pb = pbuf + s * 16 * PSTRIDE + col * PSTRIDE;
        #pragma unroll
        for (int g = 0; g < 4; g++) {
            bf16x4 pp;
            #pragma unroll
            for (int r = 0; r < 4; r++) {
                float p = __builtin_amdgcn_exp2f(st[s][g][r] * scl - 12.0f);
                if (MASK) {
                    int kv = kv0 + g * 16 + quad * 4 + r;
                    if (kv > qw + s * 16 + col) p = 0.f;
                }
                pp[r] = (__bf16)p;
            }
            *(bf16x4*)(pb + g * 16 + quad * 4) = pp;
        }
    }
    SWAITCNT("lgkmcnt(0)");   // wave-local LDS ordering for P round-trip
    bf16x8 pf[2][2];
    #pragma unroll
    for (int s = 0; s < 2; s++) {
        const __bf16* pb = pbuf + s * 16 * PSTRIDE + col * PSTRIDE;
        pf[s][0] = *(const bf16x8*)(pb + quad * 8);
        pf[s][1] = *(const bf16x8*)(pb + 32 + quad * 8);
        lacc[s] = mfma16(pf[s][1], ones, mfma16(pf[s][0], ones, lacc[s]));
    }
    #pragma unroll
    for (int dt = 0; dt < 4; dt++) {
        bf16x8 vlo = ld_sw(Vs, dt * 16 + col, 0, quad, c7);
        bf16x8 vhi = ld_sw(Vs, dt * 16 + col, 1, quad, c7);
        #pragma unroll
        for (int s = 0; s < 2; s++)
            oacc[s][dt] = mfma16(pf[s][1], vhi, mfma16(pf[s][0], vlo, oacc[s][dt]));
    }
}

__global__ __launch_bounds__(256, 3)
void k_attn(const u16* __restrict__ Q, const u16* __restrict__ Kf,
            const u16* __restrict__ Vt, u16* __restrict__ Of)
{
    __shared__ u16 Ks[2][64 * DK];
    __shared__ u16 Vs[2][64 * DK];
    __shared__ __bf16 Plds[4][32 * PSTRIDE];
    const int bh   = blockIdx.x;
    const int b    = bh / H_;
    const int h    = bh - b * H_;
    const int tid  = threadIdx.x;
    const int lane = tid & 63;
    const int w    = tid >> 6;
    const int quad = lane >> 4;
    const int col  = lane & 15;
    const int ty   = 7 - (int)blockIdx.y;
    const int nch  = 2 * ty + 2;
    const int qw   = ty * 128 + w * 32;
    __bf16* pbuf = Plds[w];

    const u16* Qb = Q  + (size_t)bh * T_ * DK;
    const u16* Kb = Kf + (size_t)bh * T_ * DK;
    const u16* Vb = Vt + (size_t)bh * DK * T_;

    int sG0 = tid, sG1 = 256 + tid;
    int sr0 = sG0 >> 3, sg0 = (sG0 & 7) ^ (sr0 & 7);
    int sr1 = sG1 >> 3, sg1 = (sG1 & 7) ^ (sr1 & 7);

    bf16x8 qf[2][2];
    #pragma unroll
    for (int s = 0; s < 2; s++) {
        const u16* qp = Qb + (size_t)(qw + s * 16 + col) * DK;
        qf[s][0] = *(const bf16x8*)(qp + quad * 8);
        qf[s][1] = *(const bf16x8*)(qp + 32 + quad * 8);
    }

    bf16x8 ones;
    #pragma unroll
    for (int i = 0; i < 8; i++) ((u16*)&ones)[i] = 0x3F80;

    f32x4 zero4 = {0.f, 0.f, 0.f, 0.f};
    f32x4 oacc[2][4];
    f32x4 lacc[2] = {zero4, zero4};
    #pragma unroll
    for (int s = 0; s < 2; s++)
        #pragma unroll
        for (int dt = 0; dt < 4; dt++) oacc[s][dt] = zero4;

    #define ASTAGE(c, bufi)                                                            \
        do {                                                                           \
            int kvs = (c) * 64;                                                        \
            gl_lds16(Kb + (size_t)(kvs + sr0) * DK + sg0 * 8, (char*)Ks[bufi] + w * 1024);        \
            gl_lds16(Kb + (size_t)(kvs + sr1) * DK + sg1 * 8, (char*)Ks[bufi] + 4096 + w * 1024); \
            gl_lds16(Vb + (size_t)sr0 * T_ + kvs + sg0 * 8,   (char*)Vs[bufi] + w * 1024);        \
            gl_lds16(Vb + (size_t)sr1 * T_ + kvs + sg1 * 8,   (char*)Vs[bufi] + 4096 + w * 1024); \
        } while (0)

    ASTAGE(0, 0);
    #pragma unroll 1
    for (int c = 0; c < nch; ++c) {
        const int cur = c & 1;
        SBARRIER();                        // readers of buf[!cur] done
        if (c + 1 < nch) {
            ASTAGE(c + 1, cur ^ 1);
            SWAITCNT("vmcnt(4)");
        } else {
            SWAITCNT("vmcnt(0)");
        }
        SBARRIER();                        // all waves' buf[cur] staged

        const int kv0 = c * 64;
        if (kv0 <= qw + 31) {
            if (kv0 + 63 <= qw)
                attn_chunk<false>(Ks[cur], Vs[cur], pbuf, qf, ones, kv0, qw, quad, col, oacc, lacc);
            else
                attn_chunk<true>(Ks[cur], Vs[cur], pbuf, qf, ones, kv0, qw, quad, col, oacc, lacc);
        }
    }
    #undef ASTAGE

    #pragma unroll
    for (int s = 0; s < 2; s++) {
        #pragma unroll
        for (int r = 0; r < 4; r++) {
            float inv = 1.f / lacc[s][r];
            int t = qw + s * 16 + quad * 4 + r;
            u16* op = Of + ((size_t)(b * T_ + t)) * C_ + h * DK;
            #pragma unroll
            for (int dt = 0; dt < 4; dt++) op[dt * 16 + col] = f2b(oacc[s][dt][r] * inv);
        }
    }
}

extern "C" void kernel_launch(void* const* d_in, const int* in_sizes, int n_in,
                              void* d_out, int out_size, void* d_ws, size_t ws_size,
                              hipStream_t stream) {
    const float* x    = (const float*)d_in[0];
    const float* Wqkv = (const float*)d_in[1];
    const float* bqkv = (const float*)d_in[2];
    const float* Wout = (const float*)d_in[3];
    const float* bout = (const float*)d_in[4];
    float* out = (float*)d_out;

    char* ws = (char*)d_ws;
    u16* xb    = (u16*)(ws);                    // 8192*768     bf16 = 12.0 MiB
    u16* wqkvT = (u16*)(ws + 12582912);         // [2304,768]   bf16
    u16* woutT = (u16*)(ws + 16121856);         // [768,768]    bf16
    u16* qw    = (u16*)(ws + 17301504);         // [96,1024,64] bf16
    u16* kw    = (u16*)(ws + 29884416);         // [96,1024,64] bf16
    u16* vtw   = (u16*)(ws + 42467328);         // [96,64,1024] bf16
    u16* aw    = (u16*)(ws + 55050240);         // [8192,768]   bf16  (end ~67.6 MB)

    k_convert<<<(BT * C_ / 4) / 256, 256, 0, stream>>>(x, xb, BT * C_ / 4);
    k_transpose_convert<<<dim3(NQKV / 32, C_ / 32), dim3(32, 8), 0, stream>>>(Wqkv, wqkvT, C_, NQKV);
    k_transpose_convert<<<dim3(C_ / 32, C_ / 32), dim3(32, 8), 0, stream>>>(Wout, woutT, C_, C_);

    k_gemm_qkv<<<dim3(NQKV / 128, BT / 128), 256, 0, stream>>>(
        xb, wqkvT, bqkv, qw, kw, vtw);

    k_attn<<<dim3(B_ * H_, 8), 256, 0, stream>>>(qw, kw, vtw, aw);

    k_gemm_out<<<dim3(C_ / 128, BT / 128), 256, 0, stream>>>(
        aw, woutT, bout, out, BT, C_, C_);
}

// Round 9
// 183.181 us; speedup vs baseline: 1.0725x; 1.0324x over previous
//
#include <hip/hip_runtime.h>
#include <stdint.h>

#define B_ 8
#define T_ 1024
#define C_ 768
#define H_ 12
#define DK 64
#define BT (B_*T_)      // 8192
#define NQKV (3*C_)     // 2304

typedef unsigned short u16;
typedef __bf16 bf16x8 __attribute__((ext_vector_type(8)));
typedef __bf16 bf16x4 __attribute__((ext_vector_type(4)));
typedef float  f32x4  __attribute__((ext_vector_type(4)));

typedef const __attribute__((address_space(1))) void gvoid_t;
typedef __attribute__((address_space(3))) void lvoid_t;

// Raw s_barrier is NOT a compiler fence (LLVM IntrNoMem) — caused R6's replay
// race. asm volatile + "memory" clobber = compiler-only fence, zero extra
// instructions, preserves fine-grained vmcnt pipelining.
#define SBARRIER()  asm volatile("s_barrier" ::: "memory")
#define SWAITCNT(s) asm volatile("s_waitcnt " s ::: "memory")

__device__ __forceinline__ void gl_lds16(const void* g, void* l) {
    __builtin_amdgcn_global_load_lds((gvoid_t*)g, (lvoid_t*)l, 16, 0, 0);
}

__device__ __forceinline__ u16 f2b(float f) {
    union { float f; unsigned int u; } v; v.f = f;
    unsigned int u = v.u;
    return (u16)((u + 0x7fffu + ((u >> 16) & 1u)) >> 16);
}

__device__ __forceinline__ f32x4 mfma16(bf16x8 a, bf16x8 b, f32x4 c) {
    return __builtin_amdgcn_mfma_f32_16x16x32_bf16(a, b, c, 0, 0, 0);
}

// ---------- merged prep: convert x + transpose both W (one launch) ----------
// blocks [0,6144): x f32->bf16 x4          (6144*256*4 = 6.29M elems)
// blocks [6144,7872): Wqkv^T 72x24 tiles
// blocks [7872,8448): Wout^T 24x24 tiles
__global__ __launch_bounds__(256)
void k_prep(const float* __restrict__ x, u16* __restrict__ xb,
            const float* __restrict__ wqkv, u16* __restrict__ wqkvT,
            const float* __restrict__ wout, u16* __restrict__ woutT)
{
    __shared__ u16 tile[32][34];
    const int bid = blockIdx.x;
    const int tid = threadIdx.x;
    if (bid < 6144) {
        int i = bid * 256 + tid;
        float4 f = ((const float4*)x)[i];
        uint2 o;
        o.x = (unsigned)f2b(f.x) | ((unsigned)f2b(f.y) << 16);
        o.y = (unsigned)f2b(f.z) | ((unsigned)f2b(f.w) << 16);
        ((uint2*)xb)[i] = o;
        return;
    }
    const float* w; u16* wt; int K, N, n0, k0;
    if (bid < 6144 + 1728) {
        int idx = bid - 6144;
        w = wqkv; wt = wqkvT; K = C_; N = NQKV;
        n0 = (idx % 72) * 32; k0 = (idx / 72) * 32;
    } else {
        int idx = bid - 7872;
        w = wout; wt = woutT; K = C_; N = C_;
        n0 = (idx % 24) * 32; k0 = (idx / 24) * 32;
    }
    const int tx = tid & 31, ty = tid >> 5;   // 32 x 8
    #pragma unroll
    for (int i = 0; i < 4; i++)
        tile[ty + i * 8][tx] = f2b(w[(size_t)(k0 + ty + i * 8) * N + n0 + tx]);
    __syncthreads();
    #pragma unroll
    for (int i = 0; i < 4; i++)
        wt[(size_t)(n0 + ty + i * 8) * K + k0 + tx] = tile[tx][ty + i * 8];
}

// ---------- QKV GEMM: 128x128 tile, 3-stage dist-2 (R5/R8 proven) ----------
__global__ __launch_bounds__(256, 3)
void k_gemm_qkv(const u16* __restrict__ A, const u16* __restrict__ Bt,
                const float* __restrict__ bias,
                u16* __restrict__ qo, u16* __restrict__ ko, u16* __restrict__ vto)
{
    const int K = C_;
    __shared__ u16 As[3][128 * 32];
    __shared__ u16 Bs[3][128 * 32];   // 48 KB -> 3 blocks/CU
    const int tid  = threadIdx.x;
    const int lane = tid & 63;
    const int w    = tid >> 6;
    const int quad = lane >> 4;
    const int col  = lane & 15;

    const int id   = blockIdx.x + gridDim.x * blockIdx.y;  // grid (18, 64)
    const int xcd  = id & 7;
    const int slot = id >> 3;
    const int m0   = (xcd * 8 + (slot & 7)) * 128;
    const int n0   = (slot >> 3) * 128;

    const int wm   = (w >> 1) * 64;
    const int wn   = (w & 1) * 64;

    f32x4 zero4 = {0.f, 0.f, 0.f, 0.f};
    f32x4 acc[4][4];
    #pragma unroll
    for (int i = 0; i < 4; i++)
        #pragma unroll
        for (int j = 0; j < 4; j++) acc[i][j] = zero4;

    const int sr  = tid >> 2;
    const int scc = ((tid & 3) ^ ((sr >> 1) & 3)) * 8;
    const u16* gA = A  + (size_t)(m0 + sr) * K + scc;
    const u16* gB = Bt + (size_t)(n0 + sr) * K + scc;

    const int NIT = K >> 5;   // 24

    #define STAGE(kt, bufi)                                                          \
        do {                                                                         \
            gl_lds16(gA + (kt),                  (char*)As[bufi] + w * 1024);        \
            gl_lds16(gA + (size_t)64 * K + (kt), (char*)As[bufi] + 4096 + w * 1024); \
            gl_lds16(gB + (kt),                  (char*)Bs[bufi] + w * 1024);        \
            gl_lds16(gB + (size_t)64 * K + (kt), (char*)Bs[bufi] + 4096 + w * 1024); \
        } while (0)

    STAGE(0, 0);
    STAGE(32, 1);
    int cur = 0;
    for (int it = 0; it < NIT; ++it) {
        SBARRIER();                        // readers of buf[(cur+2)%3] done
        if (it + 2 < NIT) {
            int b2 = cur + 2; if (b2 >= 3) b2 -= 3;
            STAGE((it + 2) << 5, b2);
            SWAITCNT("vmcnt(8)");          // drain tile `it` (issued 2 iters ago)
        } else if (it + 1 < NIT) {
            SWAITCNT("vmcnt(4)");
        } else {
            SWAITCNT("vmcnt(0)");
        }
        SBARRIER();                        // all waves' buf[cur] landed

        const u16* Ab = As[cur];
        const u16* Bb = Bs[cur];
        bf16x8 af[4], bfr[4];
        #pragma unroll
        for (int mt = 0; mt < 4; mt++) {
            int row = wm + mt * 16 + col;
            af[mt] = *(const bf16x8*)&Ab[row * 32 + ((quad ^ ((row >> 1) & 3)) * 8)];
        }
        #pragma unroll
        for (int nt = 0; nt < 4; nt++) {
            int row = wn + nt * 16 + col;
            bfr[nt] = *(const bf16x8*)&Bb[row * 32 + ((quad ^ ((row >> 1) & 3)) * 8)];
        }
        #pragma unroll
        for (int mt = 0; mt < 4; mt++)
            #pragma unroll
            for (int nt = 0; nt < 4; nt++)
                acc[mt][nt] = mfma16(af[mt], bfr[nt], acc[mt][nt]);

        cur = (cur == 2) ? 0 : cur + 1;
    }
    #undef STAGE

    #pragma unroll
    for (int mt = 0; mt < 4; mt++) {
        #pragma unroll
        for (int nt = 0; nt < 4; nt++) {
            #pragma unroll
            for (int r = 0; r < 4; r++) {
                int m = m0 + wm + mt * 16 + quad * 4 + r;
                int n = n0 + wn + nt * 16 + col;
                float v = acc[mt][nt][r] + bias[n];
                int sec = n / C_;
                int c   = n - sec * C_;
                int h   = c >> 6;
                int d   = c & 63;
                int b   = m >> 10;
                int t   = m & 1023;
                int bh  = b * H_ + h;
                u16 bv  = f2b(v);
                if (sec == 0)      qo [((size_t)bh * T_ + t) * DK + d] = bv;
                else if (sec == 1) ko [((size_t)bh * T_ + t) * DK + d] = bv;
                else               vto[((size_t)bh * DK + d) * T_ + t] = bv;
            }
        }
    }
}

// ---------- out-proj GEMM: 128x64 tiles, 768 blocks, 4 blocks/CU ----------
// R8 accounting: out-proj (384 blocks, 2/CU) is the hidden latency-bound cost.
// R7 lesson applied: maximize TLP. 36 KB LDS 3-stage dist-2; wave = 32x64.
__global__ __launch_bounds__(256, 4)
void k_gemm_out(const u16* __restrict__ A, const u16* __restrict__ Bt,
                const float* __restrict__ bias, float* __restrict__ outf)
{
    const int K = C_, N = C_;
    __shared__ u16 As[3][128 * 32];   // 3 x 8 KB
    __shared__ u16 Bs[3][64 * 32];    // 3 x 4 KB  (36 KB total)
    const int tid  = threadIdx.x;
    const int lane = tid & 63;
    const int w    = tid >> 6;
    const int quad = lane >> 4;
    const int col  = lane & 15;

    const int id   = blockIdx.x;          // 0..767
    const int xcd  = id & 7;
    const int slot = id >> 3;             // 0..95
    const int m0   = (xcd * 8 + (slot & 7)) * 128;
    const int n0   = (slot >> 3) * 64;    // 12 n-tiles

    f32x4 zero4 = {0.f, 0.f, 0.f, 0.f};
    f32x4 acc[2][4];
    #pragma unroll
    for (int i = 0; i < 2; i++)
        #pragma unroll
        for (int j = 0; j < 4; j++) acc[i][j] = zero4;

    const int sr  = tid >> 2;             // 0..63
    const int scc = ((tid & 3) ^ ((sr >> 1) & 3)) * 8;
    const u16* gA = A  + (size_t)(m0 + sr) * K + scc;
    const u16* gB = Bt + (size_t)(n0 + sr) * K + scc;   // sr < 64 rows

    const int NIT = K >> 5;   // 24

    #define STAGE(kt, bufi)                                                          \
        do {                                                                         \
            gl_lds16(gA + (kt),                  (char*)As[bufi] + w * 1024);        \
            gl_lds16(gA + (size_t)64 * K + (kt), (char*)As[bufi] + 4096 + w * 1024); \
            gl_lds16(gB + (kt),                  (char*)Bs[bufi] + w * 1024);        \
        } while (0)

    STAGE(0, 0);
    STAGE(32, 1);
    int cur = 0;
    for (int it = 0; it < NIT; ++it) {
        SBARRIER();                        // readers of buf[(cur+2)%3] done
        if (it + 2 < NIT) {
            int b2 = cur + 2; if (b2 >= 3) b2 -= 3;
            STAGE((it + 2) << 5, b2);      // 3 loads/wave
            SWAITCNT("vmcnt(6)");          // stages it+1,it+2 in flight; it drained
        } else if (it + 1 < NIT) {
            SWAITCNT("vmcnt(3)");
        } else {
            SWAITCNT("vmcnt(0)");
        }
        SBARRIER();                        // all waves' buf[cur] landed

        const u16* Ab = As[cur];
        const u16* Bb = Bs[cur];
        bf16x8 af[2], bfr[4];
        #pragma unroll
        for (int mt = 0; mt < 2; mt++) {
            int row = w * 32 + mt * 16 + col;
            af[mt] = *(const bf16x8*)&Ab[row * 32 + ((quad ^ ((row >> 1) & 3)) * 8)];
        }
        #pragma unroll
        for (int nt = 0; nt < 4; nt++) {
            int row = nt * 16 + col;
            bfr[nt] = *(const bf16x8*)&Bb[row * 32 + ((quad ^ ((row >> 1) & 3)) * 8)];
        }
        #pragma unroll
        for (int mt = 0; mt < 2; mt++)
            #pragma unroll
            for (int nt = 0; nt < 4; nt++)
                acc[mt][nt] = mfma16(af[mt], bfr[nt], acc[mt][nt]);

        cur = (cur == 2) ? 0 : cur + 1;
    }
    #undef STAGE

    #pragma unroll
    for (int mt = 0; mt < 2; mt++) {
        #pragma unroll
        for (int nt = 0; nt < 4; nt++) {
            #pragma unroll
            for (int r = 0; r < 4; r++) {
                int m = m0 + w * 32 + mt * 16 + quad * 4 + r;
                int n = n0 + nt * 16 + col;
                outf[(size_t)m * N + n] = acc[mt][nt][r] + bias[n];
            }
        }
    }
}

// ---------- causal flash attention, dbuf K/V staging (unchanged) ----------
#define PSTRIDE 72   // u16 elems; 144B rows

__device__ __forceinline__ bf16x8 ld_sw(const u16* base, int row, int half,
                                        int quad, int c7) {
    return *(const bf16x8*)(base + row * DK + (((half * 4 + quad) ^ c7) * 8));
}

template <bool MASK>
__device__ __forceinline__ void attn_chunk(
    const u16* Ks, const u16* Vs, __bf16* pbuf,
    const bf16x8 (&qf)[2][2], bf16x8 ones,
    int kv0, int qw, int quad, int col,
    f32x4 (&oacc)[2][4], f32x4 (&lacc)[2])
{
    const int c7 = col & 7;
    f32x4 zero4 = {0.f, 0.f, 0.f, 0.f};
    f32x4 st[2][4];
    #pragma unroll
    for (int g = 0; g < 4; g++) {
        bf16x8 klo = ld_sw(Ks, g * 16 + col, 0, quad, c7);
        bf16x8 khi = ld_sw(Ks, g * 16 + col, 1, quad, c7);
        st[0][g] = mfma16(khi, qf[0][1], mfma16(klo, qf[0][0], zero4));
        st[1][g] = mfma16(khi, qf[1][1], mfma16(klo, qf[1][0], zero4));
    }
    const float scl = 0.18033688f;   // log2(e)/8
    #pragma unroll
    for (int s = 0; s < 2; s++) {
        __bf16* pb = pbuf + s * 16 * PSTRIDE + col * PSTRIDE;
        #pragma unroll
        for (int g = 0; g < 4; g++) {
            bf16x4 pp;
            #pragma unroll
            for (int r = 0; r < 4; r++) {
                float p = __builtin_amdgcn_exp2f(st[s][g][r] * scl - 12.0f);
                if (MASK) {
                    int kv = kv0 + g * 16 + quad * 4 + r;
                    if (kv > qw + s * 16 + col) p = 0.f;
                }
                pp[r] = (__bf16)p;
            }
            *(bf16x4*)(pb + g * 16 + quad * 4) = pp;
        }
    }
    SWAITCNT("lgkmcnt(0)");   // wave-local LDS ordering for P round-trip
    bf16x8 pf[2][2];
    #pragma unroll
    for (int s = 0; s < 2; s++) {
        const __bf16* pb = pbuf + s * 16 * PSTRIDE + col * PSTRIDE;
        pf[s][0] = *(const bf16x8*)(pb + quad * 8);
        pf[s][1] = *(const bf16x8*)(pb + 32 + quad * 8);
        lacc[s] = mfma16(pf[s][1], ones, mfma16(pf[s][0], ones, lacc[s]));
    }
    #pragma unroll
    for (int dt = 0; dt < 4; dt++) {
        bf16x8 vlo = ld_sw(Vs, dt * 16 + col, 0, quad, c7);
        bf16x8 vhi = ld_sw(Vs, dt * 16 + col, 1, quad, c7);
        #pragma unroll
        for (int s = 0; s < 2; s++)
            oacc[s][dt] = mfma16(pf[s][1], vhi, mfma16(pf[s][0], vlo, oacc[s][dt]));
    }
}

__global__ __launch_bounds__(256, 3)
void k_attn(const u16* __restrict__ Q, const u16* __restrict__ Kf,
            const u16* __restrict__ Vt, u16* __restrict__ Of)
{
    __shared__ u16 Ks[2][64 * DK];
    __shared__ u16 Vs[2][64 * DK];
    __shared__ __bf16 Plds[4][32 * PSTRIDE];
    const int bh   = blockIdx.x;
    const int b    = bh / H_;
    const int h    = bh - b * H_;
    const int tid  = threadIdx.x;
    const int lane = tid & 63;
    const int w    = tid >> 6;
    const int quad = lane >> 4;
    const int col  = lane & 15;
    const int ty   = 7 - (int)blockIdx.y;
    const int nch  = 2 * ty + 2;
    const int qw   = ty * 128 + w * 32;
    __bf16* pbuf = Plds[w];

    const u16* Qb = Q  + (size_t)bh * T_ * DK;
    const u16* Kb = Kf + (size_t)bh * T_ * DK;
    const u16* Vb = Vt + (size_t)bh * DK * T_;

    int sG0 = tid, sG1 = 256 + tid;
    int sr0 = sG0 >> 3, sg0 = (sG0 & 7) ^ (sr0 & 7);
    int sr1 = sG1 >> 3, sg1 = (sG1 & 7) ^ (sr1 & 7);

    bf16x8 qf[2][2];
    #pragma unroll
    for (int s = 0; s < 2; s++) {
        const u16* qp = Qb + (size_t)(qw + s * 16 + col) * DK;
        qf[s][0] = *(const bf16x8*)(qp + quad * 8);
        qf[s][1] = *(const bf16x8*)(qp + 32 + quad * 8);
    }

    bf16x8 ones;
    #pragma unroll
    for (int i = 0; i < 8; i++) ((u16*)&ones)[i] = 0x3F80;

    f32x4 zero4 = {0.f, 0.f, 0.f, 0.f};
    f32x4 oacc[2][4];
    f32x4 lacc[2] = {zero4, zero4};
    #pragma unroll
    for (int s = 0; s < 2; s++)
        #pragma unroll
        for (int dt = 0; dt < 4; dt++) oacc[s][dt] = zero4;

    #define ASTAGE(c, bufi)                                                            \
        do {                                                                           \
            int kvs = (c) * 64;                                                        \
            gl_lds16(Kb + (size_t)(kvs + sr0) * DK + sg0 * 8, (char*)Ks[bufi] + w * 1024);        \
            gl_lds16(Kb + (size_t)(kvs + sr1) * DK + sg1 * 8, (char*)Ks[bufi] + 4096 + w * 1024); \
            gl_lds16(Vb + (size_t)sr0 * T_ + kvs + sg0 * 8,   (char*)Vs[bufi] + w * 1024);        \
            gl_lds16(Vb + (size_t)sr1 * T_ + kvs + sg1 * 8,   (char*)Vs[bufi] + 4096 + w * 1024); \
        } while (0)

    ASTAGE(0, 0);
    #pragma unroll 1
    for (int c = 0; c < nch; ++c) {
        const int cur = c & 1;
        SBARRIER();                        // readers of buf[!cur] done
        if (c + 1 < nch) {
            ASTAGE(c + 1, cur ^ 1);
            SWAITCNT("vmcnt(4)");
        } else {
            SWAITCNT("vmcnt(0)");
        }
        SBARRIER();                        // all waves' buf[cur] staged

        const int kv0 = c * 64;
        if (kv0 <= qw + 31) {
            if (kv0 + 63 <= qw)
                attn_chunk<false>(Ks[cur], Vs[cur], pbuf, qf, ones, kv0, qw, quad, col, oacc, lacc);
            else
                attn_chunk<true>(Ks[cur], Vs[cur], pbuf, qf, ones, kv0, qw, quad, col, oacc, lacc);
        }
    }
    #undef ASTAGE

    #pragma unroll
    for (int s = 0; s < 2; s++) {
        #pragma unroll
        for (int r = 0; r < 4; r++) {
            float inv = 1.f / lacc[s][r];
            int t = qw + s * 16 + quad * 4 + r;
            u16* op = Of + ((size_t)(b * T_ + t)) * C_ + h * DK;
            #pragma unroll
            for (int dt = 0; dt < 4; dt++) op[dt * 16 + col] = f2b(oacc[s][dt][r] * inv);
        }
    }
}

extern "C" void kernel_launch(void* const* d_in, const int* in_sizes, int n_in,
                              void* d_out, int out_size, void* d_ws, size_t ws_size,
                              hipStream_t stream) {
    const float* x    = (const float*)d_in[0];
    const float* Wqkv = (const float*)d_in[1];
    const float* bqkv = (const float*)d_in[2];
    const float* Wout = (const float*)d_in[3];
    const float* bout = (const float*)d_in[4];
    float* out = (float*)d_out;

    char* ws = (char*)d_ws;
    u16* xb    = (u16*)(ws);                    // 8192*768     bf16 = 12.0 MiB
    u16* wqkvT = (u16*)(ws + 12582912);         // [2304,768]   bf16
    u16* woutT = (u16*)(ws + 16121856);         // [768,768]    bf16
    u16* qw    = (u16*)(ws + 17301504);         // [96,1024,64] bf16
    u16* kw    = (u16*)(ws + 29884416);         // [96,1024,64] bf16
    u16* vtw   = (u16*)(ws + 42467328);         // [96,64,1024] bf16
    u16* aw    = (u16*)(ws + 55050240);         // [8192,768]   bf16  (end ~67.6 MB)

    k_prep<<<8448, 256, 0, stream>>>(x, xb, Wqkv, wqkvT, Wout, woutT);

    k_gemm_qkv<<<dim3(NQKV / 128, BT / 128), 256, 0, stream>>>(
        xb, wqkvT, bqkv, qw, kw, vtw);

    k_attn<<<dim3(B_ * H_, 8), 256, 0, stream>>>(qw, kw, vtw, aw);

    k_gemm_out<<<768, 256, 0, stream>>>(aw, woutT, bout, out);
}